// Round 18
// baseline (2132.019 us; speedup 1.0000x reference)
//
#include <hip/hip_runtime.h>
#include <cstdint>
#include <cstddef>

// ---------------------------------------------------------------------------
// TLSTM: B=64, S=512, I=256, H=256
// R18: temporal 2-cohort stagger. Grid 32 = 4 groups x 8 shards; group owns
// 16 batches = cohorts A (8) + B (8). Per iteration (one step for both):
//   MFMA_A, gates_A | w4: publish A+vmcnt+tagA  while others gather B(s)
//   MFMA_B, gates_B | flush | publish B (stores) | poll+gather A(s+1)
//   w4: (free) vmcnt + tagB
// Each cohort's publish-drain + tag-propagation RT hides under the other
// cohort's compute/gather; polls mostly hit on the first try. Exchange is
// sc0+sc1 device-scope (XCD-mapping independent, R12-proven); spin-capped.
// ---------------------------------------------------------------------------

#define B_   64
#define S_   512
#define H_   256
#define BSH_ ((size_t)B_ * S_ * H_)  // 8388608

typedef _Float16 f16;
typedef _Float16 f16x8 __attribute__((ext_vector_type(8)));
typedef short    s16x8 __attribute__((ext_vector_type(8)));
typedef float    f32x4 __attribute__((ext_vector_type(4)));
typedef unsigned int u32x4 __attribute__((ext_vector_type(4)));

static __device__ __forceinline__ unsigned short f32_to_bf16(float f) {
    union { float f; uint32_t u; } v; v.f = f;
    uint32_t u = v.u;
    u += 0x7fffu + ((u >> 16) & 1u);   // RTNE
    return (unsigned short)(u >> 16);
}

static __device__ __forceinline__ float sigm(float z) {
    return 1.0f / (1.0f + __expf(-z));
}
static __device__ __forceinline__ float tanh_fast(float z) {
    float e = __expf(-2.0f * fabsf(z));
    float t = (1.0f - e) / (1.0f + e);
    return z >= 0.0f ? t : -t;
}

// ---------------------------------------------------------------------------
// prep: W4 (bf16, [1024][256]) + fused bias4 (Wg_b + b_g + Ug_b)
// ---------------------------------------------------------------------------
__global__ void prep_w4(const float* __restrict__ Wi, const float* __restrict__ Wf,
                        const float* __restrict__ Wo, const float* __restrict__ Wc,
                        const float* __restrict__ Wib, const float* __restrict__ Wfb,
                        const float* __restrict__ Wob, const float* __restrict__ Wcb,
                        const float* __restrict__ Uib, const float* __restrict__ Ufb,
                        const float* __restrict__ Uob, const float* __restrict__ Ucb,
                        const float* __restrict__ bi,  const float* __restrict__ bf_,
                        const float* __restrict__ bo,  const float* __restrict__ bc,
                        unsigned short* __restrict__ W4, float* __restrict__ bias4) {
    const int n = blockIdx.x;        // 0..1023
    const int k = threadIdx.x;       // 0..255
    const int g = n >> 8, o = n & 255;
    const float* W = (g == 0) ? Wi : (g == 1) ? Wf : (g == 2) ? Wo : Wc;
    W4[n * 256 + k] = f32_to_bf16(W[o * 256 + k]);
    if (k == 0) {
        const float* wb = (g == 0) ? Wib : (g == 1) ? Wfb : (g == 2) ? Wob : Wcb;
        const float* ub = (g == 0) ? Uib : (g == 1) ? Ufb : (g == 2) ? Uob : Ucb;
        const float* sb = (g == 0) ? bi  : (g == 1) ? bf_ : (g == 2) ? bo  : bc;
        bias4[n] = wb[o] + ub[o] + sb[o];
    }
}

// ---------------------------------------------------------------------------
// prep: weight B-fragments, 8-shard layout, fragment-linear:
// wfg[ q*5120 + ((g*2+t)*8+ks)*64 + l ] = f16x8 of
//   U_g[ 32q + t*16 + (l&15) ][ 32ks + (l>>4)*8 .. +8 ]
// ---------------------------------------------------------------------------
__global__ void prep_wfrag(const float* __restrict__ Ui, const float* __restrict__ Uf,
                           const float* __restrict__ Uo, const float* __restrict__ Uc,
                           const float* __restrict__ Wd, uint4* __restrict__ wfg) {
    const int id = blockIdx.x * 256 + threadIdx.x;   // 0..40959
    const int l  = id & 63;
    const int ks = (id >> 6) & 7;
    const int t  = (id >> 9) & 1;
    const int qg = id >> 10;         // q*5+g, 0..39
    const int q  = qg / 5;
    const int g  = qg - q * 5;
    const float* U = (g == 0) ? Ui : (g == 1) ? Uf : (g == 2) ? Uo : (g == 3) ? Uc : Wd;
    const int row = 32 * q + t * 16 + (l & 15);
    const int k0  = 32 * ks + (l >> 4) * 8;
    const float* src = U + (size_t)row * 256 + k0;
    union { f16 h[8]; uint4 v; } pk;
    #pragma unroll
    for (int i = 0; i < 8; ++i) pk.h[i] = (f16)src[i];
    wfg[id] = pk.v;
}

// prep: Tm1[m] = 1/log(ts+2.7183) - 1
__global__ void prep_T(const float* __restrict__ tsp, float* __restrict__ Tm1) {
    const int i = blockIdx.x * 256 + threadIdx.x;   // 0..32767
    Tm1[i] = 1.0f / logf(tsp[i] + 2.7183f) - 1.0f;
}

// zero n dwords at p (runs every launch; graph replays it)
__global__ void prep_zero(unsigned int* __restrict__ p, int n) {
    const int i = blockIdx.x * 256 + threadIdx.x;
    if (i < n) p[i] = 0u;
}

// ---------------------------------------------------------------------------
// Projection GEMM: Xbuf[m][j][g] f16 (gate-interleaved; recur reads uint2).
// ---------------------------------------------------------------------------
__global__ __launch_bounds__(256) void proj_gemm(const float* __restrict__ X,
        const unsigned short* __restrict__ W4, const float* __restrict__ bias4,
        f16* __restrict__ Xbuf) {
    __shared__ __align__(16) unsigned short a_s[64 * 40];
    __shared__ __align__(16) unsigned short b_s[64 * 40];
    const int bid = blockIdx.x;
    const int m0 = (bid >> 4) * 64;
    const int n0 = (bid & 15) * 64;
    const int tid  = threadIdx.x;
    const int lane = tid & 63;
    const int w    = tid >> 6;
    const int srow = tid >> 2;
    const int scol = (tid & 3) * 8;
    const int r  = lane & 15;
    const int kg = lane >> 4;

    f32x4 acc[4] = {{0,0,0,0},{0,0,0,0},{0,0,0,0},{0,0,0,0}};

    for (int kt = 0; kt < 8; ++kt) {
        const int k0 = kt * 32;
        float4 av0 = *reinterpret_cast<const float4*>(X + (size_t)(m0 + srow) * 256 + k0 + scol);
        float4 av1 = *reinterpret_cast<const float4*>(X + (size_t)(m0 + srow) * 256 + k0 + scol + 4);
        union { unsigned short us[8]; uint4 v; } pk;
        pk.us[0] = f32_to_bf16(av0.x); pk.us[1] = f32_to_bf16(av0.y);
        pk.us[2] = f32_to_bf16(av0.z); pk.us[3] = f32_to_bf16(av0.w);
        pk.us[4] = f32_to_bf16(av1.x); pk.us[5] = f32_to_bf16(av1.y);
        pk.us[6] = f32_to_bf16(av1.z); pk.us[7] = f32_to_bf16(av1.w);
        *reinterpret_cast<uint4*>(a_s + srow * 40 + scol) = pk.v;
        uint4 bv = *reinterpret_cast<const uint4*>(W4 + (size_t)(n0 + srow) * 256 + k0 + scol);
        *reinterpret_cast<uint4*>(b_s + srow * 40 + scol) = bv;
        __syncthreads();

        s16x8 af = *reinterpret_cast<const s16x8*>(a_s + (w * 16 + r) * 40 + kg * 8);
        #pragma unroll
        for (int nt = 0; nt < 4; ++nt) {
            s16x8 bfr = *reinterpret_cast<const s16x8*>(b_s + (nt * 16 + r) * 40 + kg * 8);
            acc[nt] = __builtin_amdgcn_mfma_f32_16x16x32_bf16(af, bfr, acc[nt], 0, 0, 0);
        }
        __syncthreads();
    }
    #pragma unroll
    for (int nt = 0; nt < 4; ++nt) {
        const int n = n0 + nt * 16 + r;
        const int gidx = n >> 8, jj = n & 255;
        const float bn = bias4[n];
        #pragma unroll
        for (int reg = 0; reg < 4; ++reg) {
            const int m = m0 + w * 16 + kg * 4 + reg;
            Xbuf[((size_t)m * 256 + jj) * 4 + gidx] = (f16)(acc[nt][reg] + bn);
        }
    }
}

// ---------------------------------------------------------------------------
// Recurrence. Grid 32: G = bid&3 (group), q = bid>>2 (shard: rows [32q,32q+32)
// of all five matrices, 80KB LDS). Group serves batches 16G..16G+15 as
// cohorts A (16G+0..7) and B (16G+8..15).
// ---------------------------------------------------------------------------
__global__ __launch_bounds__(320) void recur(
        const uint4* __restrict__ wfg, const f16* __restrict__ Xbuf,
        const float* __restrict__ Wdb, const float* __restrict__ bdv,
        const float* __restrict__ Tm1,
        uint4* __restrict__ hxA, uint4* __restrict__ cxA,
        uint4* __restrict__ hxB, uint4* __restrict__ cxB,
        unsigned int* __restrict__ tagsA, unsigned int* __restrict__ tagsB,
        float* __restrict__ out) {
    extern __shared__ __align__(16) char smemraw[];
    uint4* wfr   = (uint4*)smemraw;            // 5120 units (80KB)
    float* pre   = (float*)(wfr + 5120);       // [16][164] f32 (10496B)
    f16*   stgAh = (f16*)(pre + 16 * 164);     // 256 f16
    f16*   stgAc = stgAh + 256;
    f16*   stgBh = stgAc + 256;
    f16*   stgBc = stgBh + 256;                // 2KB total staging
    float* obhA  = (float*)(stgBc + 256);      // [8][256] f32 (8KB)
    float* obcA  = obhA + 2048;
    float* obhB  = obcA + 2048;
    float* obcB  = obhB + 2048;                // 32KB obuf

    const int tid = threadIdx.x;
    const int bid = blockIdx.x;
    const int G = bid & 3;           // batch group
    const int q = bid >> 2;          // row shard 0..7
    const int g = tid >> 6;          // wave = matrix 0..4
    const int l = tid & 63;

    // ---- stage weight frags ----
    {
        const uint4* src = wfg + (size_t)q * 5120;
        #pragma unroll
        for (int i = 0; i < 16; ++i) wfr[tid + i * 320] = src[tid + i * 320];
    }
    const int gb = tid >> 5;         // batch-lane 0..7 (tid<256)
    const int jl = tid & 31;         // local j 0..31
    const int j  = 32 * q + jl;      // hidden index
    float cjA = 0.0f, cjB = 0.0f, bD = 0.0f;
    if (tid < 256) bD = Wdb[j] + bdv[j];
    __syncthreads();

    uint4* hxbA = hxA + (size_t)G * 1024;        // [par][512]
    uint4* cxbA = cxA + (size_t)G * 1024;
    uint4* hxbB = hxB + (size_t)G * 1024;
    uint4* cxbB = cxB + (size_t)G * 1024;
    unsigned int* tgA = tagsA + (size_t)G * 256; // [par][8 slots x 16dw]
    unsigned int* tgB = tagsB + (size_t)G * 256;

    // loop-carried A-operand slices (h for waves 0-3, c for wave 4)
    f16x8 A8[8], B8[8];
    #pragma unroll
    for (int p = 0; p < 8; ++p) { A8[p] = (f16x8)(f16)0; B8[p] = (f16x8)(f16)0; }

// --- helpers -------------------------------------------------------------
#define POLL_TAGS(TGPTR, TGT)                                                \
    {                                                                        \
        const unsigned int* tp_ = (TGPTR) + (l & 7) * 16;                    \
        unsigned v_; int spins_ = 0;                                         \
        for (;;) {                                                           \
            asm volatile("global_load_dword %0, %1, off sc0 sc1\n\t"         \
                         "s_waitcnt vmcnt(0)"                                \
                         : "=v"(v_) : "v"(tp_) : "memory");                  \
            if (__all((int)(v_ >= (unsigned)(TGT)))) break;                  \
            if (++spins_ > (1 << 18)) break;                                 \
            __builtin_amdgcn_s_sleep(1);                                     \
        }                                                                    \
    }

#define GATHER8(DST, BASEPTR)                                                \
    {                                                                        \
        const uint4* b0_ = (BASEPTR);                                        \
        const uint4* b1_ = b0_ + 256;                                        \
        u32x4 r0_, r1_, r2_, r3_, r4_, r5_, r6_, r7_;                        \
        asm volatile(                                                        \
            "global_load_dwordx4 %0, %8, off sc0 sc1\n\t"                    \
            "global_load_dwordx4 %1, %8, off offset:1024 sc0 sc1\n\t"        \
            "global_load_dwordx4 %2, %8, off offset:2048 sc0 sc1\n\t"        \
            "global_load_dwordx4 %3, %8, off offset:3072 sc0 sc1\n\t"        \
            "global_load_dwordx4 %4, %9, off sc0 sc1\n\t"                    \
            "global_load_dwordx4 %5, %9, off offset:1024 sc0 sc1\n\t"        \
            "global_load_dwordx4 %6, %9, off offset:2048 sc0 sc1\n\t"        \
            "global_load_dwordx4 %7, %9, off offset:3072 sc0 sc1\n\t"        \
            "s_waitcnt vmcnt(0)"                                             \
            : "=&v"(r0_), "=&v"(r1_), "=&v"(r2_), "=&v"(r3_),                \
              "=&v"(r4_), "=&v"(r5_), "=&v"(r6_), "=&v"(r7_)                 \
            : "v"(b0_), "v"(b1_)                                             \
            : "memory");                                                     \
        DST[0] = __builtin_bit_cast(f16x8, r0_);                             \
        DST[1] = __builtin_bit_cast(f16x8, r1_);                             \
        DST[2] = __builtin_bit_cast(f16x8, r2_);                             \
        DST[3] = __builtin_bit_cast(f16x8, r3_);                             \
        DST[4] = __builtin_bit_cast(f16x8, r4_);                             \
        DST[5] = __builtin_bit_cast(f16x8, r5_);                             \
        DST[6] = __builtin_bit_cast(f16x8, r6_);                             \
        DST[7] = __builtin_bit_cast(f16x8, r7_);                             \
    }

#define PUBLISH64(STGH, STGC, HX, CX, PAR)                                   \
    {                                                                        \
        const int lm_ = l & 31;                                              \
        const int kg_ = lm_ >> 3, b_ = lm_ & 7;                              \
        const bool isC_ = l >= 32;                                           \
        u32x4 v_ = __builtin_bit_cast(u32x4, *reinterpret_cast<const uint4*>(\
            (isC_ ? (STGC) : (STGH)) + b_ * 32 + kg_ * 8));                  \
        uint4* pp_ = (isC_ ? (CX) : (HX)) + (PAR) * 512 + q * 64 + kg_ * 16 + b_; \
        asm volatile("global_store_dwordx4 %0, %1, off sc0 sc1"              \
                     :: "v"(pp_), "v"(v_) : "memory");                       \
    }

#define MFMA_PASS(SRC)                                                       \
    {                                                                        \
        f32x4 acc0 = {0.f, 0.f, 0.f, 0.f};                                   \
        f32x4 acc1 = {0.f, 0.f, 0.f, 0.f};                                   \
        _Pragma("unroll")                                                    \
        for (int p = 0; p < 8; ++p) {                                        \
            f16x8 b0 = __builtin_bit_cast(f16x8, wfr[((g * 2 + 0) * 8 + p) * 64 + l]); \
            f16x8 b1 = __builtin_bit_cast(f16x8, wfr[((g * 2 + 1) * 8 + p) * 64 + l]); \
            acc0 = __builtin_amdgcn_mfma_f32_16x16x32_f16(SRC[p], b0, acc0, 0, 0, 0);  \
            acc1 = __builtin_amdgcn_mfma_f32_16x16x32_f16(SRC[p], b1, acc1, 0, 0, 0);  \
        }                                                                    \
        const int mb_ = (l >> 4) * 4;                                        \
        const int c0_ = g * 32 + (l & 15);                                   \
        _Pragma("unroll")                                                    \
        for (int reg = 0; reg < 4; ++reg) {                                  \
            pre[(mb_ + reg) * 164 + c0_]      = acc0[reg];                   \
            pre[(mb_ + reg) * 164 + c0_ + 16] = acc1[reg];                   \
        }                                                                    \
    }

#define GATES(XV, TM, CJ, STGH, STGC, OBH, OBC)                              \
    {                                                                        \
        const float* pb_ = pre + gb * 164;                                   \
        const f16* xp_ = reinterpret_cast<const f16*>(&(XV));                \
        float CST_  = tanh_fast(pb_[128 + jl] + bD);                         \
        float cdec_ = (CJ) + (TM) * CST_;                                    \
        float ig_ = sigm((float)xp_[0] + pb_[jl]);                           \
        float fg_ = sigm((float)xp_[1] + pb_[32 + jl]);                      \
        float og_ = sigm((float)xp_[2] + pb_[64 + jl]);                      \
        float Cn_ = tanh_fast((float)xp_[3] + pb_[96 + jl]);                 \
        (CJ) = fg_ * cdec_ + ig_ * Cn_;                                      \
        float hn_ = og_ * tanh_fast(CJ);                                     \
        (OBH)[(s & 7) * 256 + tid] = hn_;                                    \
        (OBC)[(s & 7) * 256 + tid] = (CJ);                                   \
        (STGH)[tid] = (f16)hn_;                                              \
        (STGC)[tid] = (f16)(CJ);                                             \
    }
// -------------------------------------------------------------------------

    for (int s = 0; s < 512; ++s) {
        const int par  = s & 1;
        const int parB = (s - 1) & 1;

        // prefetch cohort-A gate inputs
        uint2 xvA = {0, 0};
        float tmA = 0.f;
        if (tid < 256) {
            const size_t m = (size_t)(16 * G + gb) * 512 + s;
            xvA = *reinterpret_cast<const uint2*>(Xbuf + (m * 256 + j) * 4);
            tmA = Tm1[m];
        }

        MFMA_PASS(A8)
        __syncthreads();                          // B1: pre_A ready
        if (tid < 256) GATES(xvA, tmA, cjA, stgAh, stgAc, obhA, obcA)
        __syncthreads();                          // B2: stgA ready

        // wave4: publish A + drain + tagA  (others gather B meanwhile)
        if (g == 4 && s != 511) {
            PUBLISH64(stgAh, stgAc, hxbA, cxbA, par)
            asm volatile("s_waitcnt vmcnt(0)" ::: "memory");
            if (l == 0) {
                unsigned int* tp = tgA + par * 128 + q * 16;
                unsigned tv = (unsigned)(s + 1);
                asm volatile("global_store_dword %0, %1, off sc0 sc1"
                             :: "v"(tp), "v"(tv) : "memory");
            }
        }
        // all: gather B(s) (published last iteration; tag ~2.5RT old)
        if (s > 0) {
            POLL_TAGS(tgB + parB * 128, s)
            GATHER8(B8, ((g == 4) ? cxbB : hxbB) + parB * 512 + l)
        }

        // prefetch cohort-B gate inputs
        uint2 xvB = {0, 0};
        float tmB = 0.f;
        if (tid < 256) {
            const size_t m = (size_t)(16 * G + 8 + gb) * 512 + s;
            xvB = *reinterpret_cast<const uint2*>(Xbuf + (m * 256 + j) * 4);
            tmB = Tm1[m];
        }

        MFMA_PASS(B8)
        __syncthreads();                          // B1': pre_B ready
        if (tid < 256) GATES(xvB, tmB, cjB, stgBh, stgBc, obhB, obcB)
        __syncthreads();                          // B2': stgB ready

        // output flush every 8 steps (stores drain under the tail)
        if ((s & 7) == 7 && tid < 256) {
            #pragma unroll
            for (int sf = 0; sf < 8; ++sf) {
                const size_t mA = (size_t)(16 * G + gb) * 512 + (s - 7 + sf);
                const size_t oiA = mA * 256 + j;
                float hv = obhA[sf * 256 + tid];
                float cv = obcA[sf * 256 + tid];
                out[oiA] = hv; out[BSH_ + oiA] = hv; out[2 * BSH_ + oiA] = cv;
                const size_t mB = (size_t)(16 * G + 8 + gb) * 512 + (s - 7 + sf);
                const size_t oiB = mB * 256 + j;
                hv = obhB[sf * 256 + tid];
                cv = obcB[sf * 256 + tid];
                out[oiB] = hv; out[BSH_ + oiB] = hv; out[2 * BSH_ + oiB] = cv;
            }
        }

        // wave4: publish B stores only (drain deferred)
        if (g == 4 && s != 511) {
            PUBLISH64(stgBh, stgBc, hxbB, cxbB, par)
        }
        // all: poll + gather A(s+1) (tagA issued ~2RT ago)
        if (s != 511) {
            POLL_TAGS(tgA + par * 128, s + 1)
            GATHER8(A8, ((g == 4) ? cxbA : hxbA) + par * 512 + l)
        }
        // wave4: B stores drained during poll/gather -> free vmcnt + tagB
        if (g == 4 && s != 511) {
            asm volatile("s_waitcnt vmcnt(0)" ::: "memory");
            if (l == 0) {
                unsigned int* tp = tgB + par * 128 + q * 16;
                unsigned tv = (unsigned)(s + 1);
                asm volatile("global_store_dword %0, %1, off sc0 sc1"
                             :: "v"(tp), "v"(tv) : "memory");
            }
        }
    }
#undef POLL_TAGS
#undef GATHER8
#undef PUBLISH64
#undef MFMA_PASS
#undef GATES
}

// ---------------------------------------------------------------------------
extern "C" void kernel_launch(void* const* d_in, const int* in_sizes, int n_in,
                              void* d_out, int out_size, void* d_ws, size_t ws_size,
                              hipStream_t stream) {
    const float* inputs = (const float*)d_in[0];
    const float* tsp    = (const float*)d_in[1];
    const float* Wi_w = (const float*)d_in[2],  * Wi_b = (const float*)d_in[3];
    const float* Ui_w = (const float*)d_in[4],  * Ui_b = (const float*)d_in[5];
    const float* Wf_w = (const float*)d_in[6],  * Wf_b = (const float*)d_in[7];
    const float* Uf_w = (const float*)d_in[8],  * Uf_b = (const float*)d_in[9];
    const float* Wo_w = (const float*)d_in[10], * Wo_b = (const float*)d_in[11];
    const float* Uo_w = (const float*)d_in[12], * Uo_b = (const float*)d_in[13];
    const float* Wc_w = (const float*)d_in[14], * Wc_b = (const float*)d_in[15];
    const float* Uc_w = (const float*)d_in[16], * Uc_b = (const float*)d_in[17];
    const float* Wd_w = (const float*)d_in[18], * Wd_b = (const float*)d_in[19];
    const float* bi = (const float*)d_in[20], * bf_ = (const float*)d_in[21];
    const float* bo = (const float*)d_in[22], * bc  = (const float*)d_in[23];
    const float* bd = (const float*)d_in[24];

    // workspace layout (16B-aligned):
    //   Xbuf  f16   [32768][256][4]  67,108,864 B @ 0
    //   W4    bf16  [1024][256]         524,288 B @ 67,108,864
    //   bias4 f32   [1024]                4,096 B @ 67,633,152
    //   wfg   uint4 [40960]             655,360 B @ 67,637,248
    //   hxA   uint4 [4][2][512]          65,536 B @ 68,292,608
    //   cxA   uint4 [4][2][512]          65,536 B @ 68,358,144
    //   hxB   uint4 [4][2][512]          65,536 B @ 68,423,680
    //   cxB   uint4 [4][2][512]          65,536 B @ 68,489,216
    //   tagsA u32   [4][2][8][16]         4,096 B @ 68,554,752   <- zeroed
    //   tagsB u32   [4][2][8][16]         4,096 B @ 68,558,848   <- zeroed
    //   Tm1   f32   [32768]             131,072 B @ 68,562,944
    char* ws = (char*)d_ws;
    f16*            Xbuf  = (f16*)ws;
    unsigned short* W4    = (unsigned short*)(ws + 67108864);
    float*          bias4 = (float*)(ws + 67633152);
    uint4*          wfg   = (uint4*)(ws + 67637248);
    uint4*          hxA   = (uint4*)(ws + 68292608);
    uint4*          cxA   = (uint4*)(ws + 68358144);
    uint4*          hxB   = (uint4*)(ws + 68423680);
    uint4*          cxB   = (uint4*)(ws + 68489216);
    unsigned int*   tagsA = (unsigned int*)(ws + 68554752);
    unsigned int*   tagsB = (unsigned int*)(ws + 68558848);
    float*          Tm1   = (float*)(ws + 68562944);

    prep_w4<<<1024, 256, 0, stream>>>(Wi_w, Wf_w, Wo_w, Wc_w,
                                      Wi_b, Wf_b, Wo_b, Wc_b,
                                      Ui_b, Uf_b, Uo_b, Uc_b,
                                      bi, bf_, bo, bc, W4, bias4);
    prep_wfrag<<<160, 256, 0, stream>>>(Ui_w, Uf_w, Uo_w, Uc_w, Wd_w, wfg);
    prep_T<<<128, 256, 0, stream>>>(tsp, Tm1);
    prep_zero<<<8, 256, 0, stream>>>(tagsA, 2048);   // tagsA+tagsB contiguous
    proj_gemm<<<8192, 256, 0, stream>>>(inputs, W4, bias4, Xbuf);

    const size_t lds_bytes = 5120 * 16 + 16 * 164 * 4
                           + 4 * 256 * 2 + 4 * 2048 * 4;   // 127,232 B
    recur<<<32, 320, lds_bytes, stream>>>(wfg, Xbuf, Wd_b, bd, Tm1,
                                          hxA, cxA, hxB, cxB,
                                          tagsA, tagsB, (float*)d_out);
}

// Round 19
// 1484.821 us; speedup vs baseline: 1.4359x; 1.4359x over previous
//
#include <hip/hip_runtime.h>
#include <cstdint>
#include <cstddef>

// ---------------------------------------------------------------------------
// TLSTM: B=64, S=512, I=256, H=256
// R19 = R12 (best: 1205us recur) with ONE change: the 16-partner tag poll
// moves from wave 0 (tid<16, where it serialized behind publish+vmcnt+tag)
// to wave 4 (tid 256..271), so partner detection starts right after B2 and
// overlaps our own publish-drain RT. Everything else byte-identical to R12:
// 16 shards x 4 groups (grid 128, G=bid&7<4), sc0 sc1 device-scope exchange
// via Infinity Cache, wide publish / tiny tag poll / wide gather, parity
// double-buffer, LDS h/c fragments.
// ---------------------------------------------------------------------------

#define B_   64
#define S_   512
#define H_   256
#define BSH_ ((size_t)B_ * S_ * H_)  // 8388608

typedef _Float16 f16;
typedef _Float16 f16x8 __attribute__((ext_vector_type(8)));
typedef short    s16x8 __attribute__((ext_vector_type(8)));
typedef float    f32x4 __attribute__((ext_vector_type(4)));
typedef unsigned int u32x4 __attribute__((ext_vector_type(4)));

static __device__ __forceinline__ unsigned short f32_to_bf16(float f) {
    union { float f; uint32_t u; } v; v.f = f;
    uint32_t u = v.u;
    u += 0x7fffu + ((u >> 16) & 1u);   // RTNE
    return (unsigned short)(u >> 16);
}

static __device__ __forceinline__ float sigm(float z) {
    return 1.0f / (1.0f + __expf(-z));
}
static __device__ __forceinline__ float tanh_fast(float z) {
    float e = __expf(-2.0f * fabsf(z));
    float t = (1.0f - e) / (1.0f + e);
    return z >= 0.0f ? t : -t;
}

// ---------------------------------------------------------------------------
// prep: W4 (bf16, [1024][256]) + fused bias4 (Wg_b + b_g + Ug_b)
// ---------------------------------------------------------------------------
__global__ void prep_w4(const float* __restrict__ Wi, const float* __restrict__ Wf,
                        const float* __restrict__ Wo, const float* __restrict__ Wc,
                        const float* __restrict__ Wib, const float* __restrict__ Wfb,
                        const float* __restrict__ Wob, const float* __restrict__ Wcb,
                        const float* __restrict__ Uib, const float* __restrict__ Ufb,
                        const float* __restrict__ Uob, const float* __restrict__ Ucb,
                        const float* __restrict__ bi,  const float* __restrict__ bf_,
                        const float* __restrict__ bo,  const float* __restrict__ bc,
                        unsigned short* __restrict__ W4, float* __restrict__ bias4) {
    const int n = blockIdx.x;        // 0..1023
    const int k = threadIdx.x;       // 0..255
    const int g = n >> 8, o = n & 255;
    const float* W = (g == 0) ? Wi : (g == 1) ? Wf : (g == 2) ? Wo : Wc;
    W4[n * 256 + k] = f32_to_bf16(W[o * 256 + k]);
    if (k == 0) {
        const float* wb = (g == 0) ? Wib : (g == 1) ? Wfb : (g == 2) ? Wob : Wcb;
        const float* ub = (g == 0) ? Uib : (g == 1) ? Ufb : (g == 2) ? Uob : Ucb;
        const float* sb = (g == 0) ? bi  : (g == 1) ? bf_ : (g == 2) ? bo  : bc;
        bias4[n] = wb[o] + ub[o] + sb[o];
    }
}

// ---------------------------------------------------------------------------
// prep: weight B-fragments, fragment-linear:
// wfg[ ((q*5+g)*8+ks)*64 + l ] (uint4) = f16x8 of
//   U_g[ 16q + (l&15) ][ 32ks + (l>>4)*8 .. +8 ]
// ---------------------------------------------------------------------------
__global__ void prep_wfrag(const float* __restrict__ Ui, const float* __restrict__ Uf,
                           const float* __restrict__ Uo, const float* __restrict__ Uc,
                           const float* __restrict__ Wd, uint4* __restrict__ wfg) {
    const int id = blockIdx.x * 256 + threadIdx.x;   // 0..40959
    const int l  = id & 63;
    const int ks = (id >> 6) & 7;
    const int qg = id >> 9;          // 0..79
    const int q  = qg / 5;
    const int g  = qg - q * 5;
    const float* U = (g == 0) ? Ui : (g == 1) ? Uf : (g == 2) ? Uo : (g == 3) ? Uc : Wd;
    const int row = 16 * q + (l & 15);
    const int k0  = 32 * ks + (l >> 4) * 8;
    const float* src = U + (size_t)row * 256 + k0;
    union { f16 h[8]; uint4 v; } pk;
    #pragma unroll
    for (int i = 0; i < 8; ++i) pk.h[i] = (f16)src[i];
    wfg[id] = pk.v;
}

// prep: Tm1[m] = 1/log(ts+2.7183) - 1
__global__ void prep_T(const float* __restrict__ tsp, float* __restrict__ Tm1) {
    const int i = blockIdx.x * 256 + threadIdx.x;   // 0..32767
    Tm1[i] = 1.0f / logf(tsp[i] + 2.7183f) - 1.0f;
}

// zero the sync tags (runs every launch; graph replays it)
__global__ void prep_zero(unsigned int* __restrict__ tags) {
    tags[blockIdx.x * 256 + threadIdx.x] = 0u;
}

// ---------------------------------------------------------------------------
// Projection GEMM: Xbuf[m][j][g] f16 (gate-interleaved; recur reads uint2).
// ---------------------------------------------------------------------------
__global__ __launch_bounds__(256) void proj_gemm(const float* __restrict__ X,
        const unsigned short* __restrict__ W4, const float* __restrict__ bias4,
        f16* __restrict__ Xbuf) {
    __shared__ __align__(16) unsigned short a_s[64 * 40];
    __shared__ __align__(16) unsigned short b_s[64 * 40];
    const int bid = blockIdx.x;
    const int m0 = (bid >> 4) * 64;
    const int n0 = (bid & 15) * 64;
    const int tid  = threadIdx.x;
    const int lane = tid & 63;
    const int w    = tid >> 6;
    const int srow = tid >> 2;
    const int scol = (tid & 3) * 8;
    const int r  = lane & 15;
    const int kg = lane >> 4;

    f32x4 acc[4] = {{0,0,0,0},{0,0,0,0},{0,0,0,0},{0,0,0,0}};

    for (int kt = 0; kt < 8; ++kt) {
        const int k0 = kt * 32;
        float4 av0 = *reinterpret_cast<const float4*>(X + (size_t)(m0 + srow) * 256 + k0 + scol);
        float4 av1 = *reinterpret_cast<const float4*>(X + (size_t)(m0 + srow) * 256 + k0 + scol + 4);
        union { unsigned short us[8]; uint4 v; } pk;
        pk.us[0] = f32_to_bf16(av0.x); pk.us[1] = f32_to_bf16(av0.y);
        pk.us[2] = f32_to_bf16(av0.z); pk.us[3] = f32_to_bf16(av0.w);
        pk.us[4] = f32_to_bf16(av1.x); pk.us[5] = f32_to_bf16(av1.y);
        pk.us[6] = f32_to_bf16(av1.z); pk.us[7] = f32_to_bf16(av1.w);
        *reinterpret_cast<uint4*>(a_s + srow * 40 + scol) = pk.v;
        uint4 bv = *reinterpret_cast<const uint4*>(W4 + (size_t)(n0 + srow) * 256 + k0 + scol);
        *reinterpret_cast<uint4*>(b_s + srow * 40 + scol) = bv;
        __syncthreads();

        s16x8 af = *reinterpret_cast<const s16x8*>(a_s + (w * 16 + r) * 40 + kg * 8);
        #pragma unroll
        for (int nt = 0; nt < 4; ++nt) {
            s16x8 bfr = *reinterpret_cast<const s16x8*>(b_s + (nt * 16 + r) * 40 + kg * 8);
            acc[nt] = __builtin_amdgcn_mfma_f32_16x16x32_bf16(af, bfr, acc[nt], 0, 0, 0);
        }
        __syncthreads();
    }
    #pragma unroll
    for (int nt = 0; nt < 4; ++nt) {
        const int n = n0 + nt * 16 + r;
        const int gidx = n >> 8, jj = n & 255;
        const float bn = bias4[n];
        #pragma unroll
        for (int reg = 0; reg < 4; ++reg) {
            const int m = m0 + w * 16 + kg * 4 + reg;
            Xbuf[((size_t)m * 256 + jj) * 4 + gidx] = (f16)(acc[nt][reg] + bn);
        }
    }
}

// ---------------------------------------------------------------------------
// Recurrence. Grid 128; real blocks: G = bid&7 (<4), q = bid>>3 (0..15).
// ---------------------------------------------------------------------------
__global__ __launch_bounds__(320) void recur(
        const uint4* __restrict__ wfg, const f16* __restrict__ Xbuf,
        const float* __restrict__ Wdb, const float* __restrict__ bdv,
        const float* __restrict__ Tm1,
        uint4* __restrict__ hxf, uint4* __restrict__ cxf,
        unsigned int* __restrict__ tags, float* __restrict__ out) {
    extern __shared__ __align__(16) char smemraw[];
    uint4* wfr  = (uint4*)smemraw;            // 2560 units (40KB)
    uint4* hfr  = wfr + 2560;                 // 512 units  (8KB)
    uint4* cfr  = hfr + 512;                  // 512 units  (8KB)
    float* pre  = (float*)(cfr + 512);        // [16][89] f32 (5696B)
    f16*   stgh = (f16*)(pre + 16 * 89);      // 256 f16 (512B)
    f16*   stgc = stgh + 256;                 // 256 f16
    float* obh  = (float*)(stgc + 256);       // [8][256] f32 (8KB)
    float* obc  = obh + 2048;                 // [8][256] f32

    const int tid = threadIdx.x;
    const int bid = blockIdx.x;
    const int G = bid & 7;           // batch group (perf-only XCD affinity)
    const int q = bid >> 3;          // row shard 0..15
    if (G >= 4) return;              // dummy block
    const int g = tid >> 6;          // wave = matrix 0..4
    const int l = tid & 63;

    // ---- stage weight frags (global fragment-linear -> LDS linear) ----
    {
        const uint4* src = wfg + (size_t)q * 2560;
        #pragma unroll
        for (int i = 0; i < 8; ++i) wfr[tid + i * 320] = src[tid + i * 320];
    }
    // ---- zero h/c frags ----
    if (tid < 256) {
        uint4 z = {0, 0, 0, 0};
        hfr[tid] = z; hfr[tid + 256] = z;
        cfr[tid] = z; cfr[tid + 256] = z;
    }
    // gate-thread state
    const int gb = tid >> 4;         // batch 0..15  (tid<256)
    const int jl = tid & 15;         // local j
    const int j  = 16 * q + jl;      // hidden index
    float cj = 0.0f, bD = 0.0f;
    if (tid < 256) bD = Wdb[j] + bdv[j];
    __syncthreads();

    const uint4* afr = (g == 4) ? cfr : hfr;
    uint4* hxb = hxf + (size_t)G * 1024;      // [par][512]
    uint4* cxb = cxf + (size_t)G * 1024;
    unsigned int* tg = tags + (size_t)G * 512; // [par][16 slots x 16dw]

    for (int s = 0; s < 512; ++s) {
        const int par = s & 1;

        // prefetch gate inputs (consumed after barrier 1)
        uint2 xv = {0, 0};
        float tm1 = 0.f;
        size_t m = 0;
        if (tid < 256) {
            m = (size_t)(16 * G + gb) * 512 + s;
            xv  = *reinterpret_cast<const uint2*>(Xbuf + (m * 256 + j) * 4);
            tm1 = Tm1[m];
        }

        // ---- MFMA matvec: pre[batch][g*16 + jl] ----
        f32x4 acc = {0.f, 0.f, 0.f, 0.f};
        #pragma unroll
        for (int ks = 0; ks < 8; ++ks) {
            f16x8 a  = __builtin_bit_cast(f16x8, afr[ks * 64 + l]);
            f16x8 bb = __builtin_bit_cast(f16x8, wfr[(g * 8 + ks) * 64 + l]);
            acc = __builtin_amdgcn_mfma_f32_16x16x32_f16(a, bb, acc, 0, 0, 0);
        }
        {
            const int mb = (l >> 4) * 4;          // batch base (D rows)
            const int nn = g * 16 + (l & 15);     // local row (D col)
            #pragma unroll
            for (int reg = 0; reg < 4; ++reg)
                pre[(mb + reg) * 89 + nn] = acc[reg];
        }
        __syncthreads();                          // B1: preacts ready

        // ---- gates (threads 0..255, 1 (batch,j) pair each) ----
        if (tid < 256) {
            const float* pb = pre + gb * 89;
            const f16* xp = reinterpret_cast<const f16*>(&xv);
            float CST  = tanh_fast(pb[64 + jl] + bD);
            float cdec = cj + tm1 * CST;
            float ig = sigm((float)xp[0] + pb[jl]);
            float fg = sigm((float)xp[1] + pb[16 + jl]);
            float og = sigm((float)xp[2] + pb[32 + jl]);
            float Cn = tanh_fast((float)xp[3] + pb[48 + jl]);
            cj = fg * cdec + ig * Cn;
            float hn = og * tanh_fast(cj);
            stgh[tid] = (f16)hn;
            stgc[tid] = (f16)cj;
            obh[(s & 7) * 256 + tid] = hn;
            obc[(s & 7) * 256 + tid] = cj;
        }
        __syncthreads();                          // B2: staging/obuf ready

        if (s != 511) {
            // ---- wave 4 (tid 256..271): poll 16 partner tags — starts
            // immediately after B2, overlapping wave 0's publish+drain+tag ----
            if (tid >= 256 && tid < 272) {
                const unsigned int* tp = tg + par * 256 + (tid - 256) * 16;
                unsigned v;
                int spins = 0;
                for (;;) {
                    asm volatile("global_load_dword %0, %1, off sc0 sc1\n\t"
                                 "s_waitcnt vmcnt(0)"
                                 : "=v"(v) : "v"(tp) : "memory");
                    if (v >= (unsigned)(s + 1)) break;
                    if (++spins > (1 << 22)) break;   // timeout insurance only
                    __builtin_amdgcn_s_sleep(1);
                }
            }
            // ---- wave 0: publish own h/c chunk via IC (sc0 sc1) + tag ----
            if (tid < 64) {
                const int b   = tid & 15;
                const int kgo = (tid >> 4) & 1;
                const bool isC = tid >= 32;
                u32x4 v = __builtin_bit_cast(u32x4, *reinterpret_cast<const uint4*>(
                    (isC ? stgc : stgh) + b * 16 + kgo * 8));
                const int u = (q >> 1) * 64 + ((q & 1) * 2 + kgo) * 16 + b;
                uint4* pp = (isC ? cxb : hxb) + par * 512 + u;
                asm volatile("global_store_dwordx4 %0, %1, off sc0 sc1"
                             :: "v"(pp), "v"(v) : "memory");
                // publish stores acked at the coherence point -> release tag
                asm volatile("s_waitcnt vmcnt(0)" ::: "memory");
                if (tid == 0) {
                    unsigned int* tp = tg + par * 256 + q * 16;
                    unsigned tagv = (unsigned)(s + 1);
                    asm volatile("global_store_dword %0, %1, off sc0 sc1"
                                 :: "v"(tp), "v"(tagv) : "memory");
                }
            }
        }
        // ---- output flush every 8 steps (overlaps partner wait) ----
        if ((s & 7) == 7 && tid < 256) {
            #pragma unroll
            for (int sf = 0; sf < 8; ++sf) {
                const size_t mm = (size_t)(16 * G + gb) * 512 + (s - 7 + sf);
                const size_t oi = mm * 256 + j;
                float hv = obh[sf * 256 + tid];
                float cv = obc[sf * 256 + tid];
                out[oi] = hv; out[BSH_ + oi] = hv; out[2 * BSH_ + oi] = cv;
            }
        }
        if (s != 511) {
            __syncthreads();                      // B3: all chunks published
            // ---- gather full h/c frags from IC (sc0 sc1, pipelined) ----
            if (tid < 256) {
                const uint4* p0 = hxb + par * 512 + tid;
                const uint4* p1 = hxb + par * 512 + tid + 256;
                const uint4* p2 = cxb + par * 512 + tid;
                const uint4* p3 = cxb + par * 512 + tid + 256;
                u32x4 va, vb, vc, vd;
                asm volatile(
                    "global_load_dwordx4 %0, %4, off sc0 sc1\n\t"
                    "global_load_dwordx4 %1, %5, off sc0 sc1\n\t"
                    "global_load_dwordx4 %2, %6, off sc0 sc1\n\t"
                    "global_load_dwordx4 %3, %7, off sc0 sc1\n\t"
                    "s_waitcnt vmcnt(0)"
                    : "=&v"(va), "=&v"(vb), "=&v"(vc), "=&v"(vd)
                    : "v"(p0), "v"(p1), "v"(p2), "v"(p3)
                    : "memory");
                hfr[tid]       = __builtin_bit_cast(uint4, va);
                hfr[tid + 256] = __builtin_bit_cast(uint4, vb);
                cfr[tid]       = __builtin_bit_cast(uint4, vc);
                cfr[tid + 256] = __builtin_bit_cast(uint4, vd);
            }
        }
        __syncthreads();                          // B4: frags ready / flush done
    }
}

// ---------------------------------------------------------------------------
extern "C" void kernel_launch(void* const* d_in, const int* in_sizes, int n_in,
                              void* d_out, int out_size, void* d_ws, size_t ws_size,
                              hipStream_t stream) {
    const float* inputs = (const float*)d_in[0];
    const float* tsp    = (const float*)d_in[1];
    const float* Wi_w = (const float*)d_in[2],  * Wi_b = (const float*)d_in[3];
    const float* Ui_w = (const float*)d_in[4],  * Ui_b = (const float*)d_in[5];
    const float* Wf_w = (const float*)d_in[6],  * Wf_b = (const float*)d_in[7];
    const float* Uf_w = (const float*)d_in[8],  * Uf_b = (const float*)d_in[9];
    const float* Wo_w = (const float*)d_in[10], * Wo_b = (const float*)d_in[11];
    const float* Uo_w = (const float*)d_in[12], * Uo_b = (const float*)d_in[13];
    const float* Wc_w = (const float*)d_in[14], * Wc_b = (const float*)d_in[15];
    const float* Uc_w = (const float*)d_in[16], * Uc_b = (const float*)d_in[17];
    const float* Wd_w = (const float*)d_in[18], * Wd_b = (const float*)d_in[19];
    const float* bi = (const float*)d_in[20], * bf_ = (const float*)d_in[21];
    const float* bo = (const float*)d_in[22], * bc  = (const float*)d_in[23];
    const float* bd = (const float*)d_in[24];

    // workspace layout (16B-aligned):
    //   Xbuf  f16   [32768][256][4]  67,108,864 B @ 0
    //   W4    bf16  [1024][256]         524,288 B @ 67,108,864
    //   bias4 f32   [1024]                4,096 B @ 67,633,152
    //   wfg   uint4 [40960]             655,360 B @ 67,637,248
    //   hxf   uint4 [4][2][512]          65,536 B @ 68,292,608
    //   cxf   uint4 [4][2][512]          65,536 B @ 68,358,144
    //   Tm1   f32   [32768]             131,072 B @ 68,423,680
    //   tags  u32   [4][2][16][16]        8,192 B @ 68,554,752
    char* ws = (char*)d_ws;
    f16*            Xbuf  = (f16*)ws;
    unsigned short* W4    = (unsigned short*)(ws + 67108864);
    float*          bias4 = (float*)(ws + 67633152);
    uint4*          wfg   = (uint4*)(ws + 67637248);
    uint4*          hxf   = (uint4*)(ws + 68292608);
    uint4*          cxf   = (uint4*)(ws + 68358144);
    float*          Tm1   = (float*)(ws + 68423680);
    unsigned int*   tags  = (unsigned int*)(ws + 68554752);

    prep_w4<<<1024, 256, 0, stream>>>(Wi_w, Wf_w, Wo_w, Wc_w,
                                      Wi_b, Wf_b, Wo_b, Wc_b,
                                      Ui_b, Uf_b, Uo_b, Uc_b,
                                      bi, bf_, bo, bc, W4, bias4);
    prep_wfrag<<<160, 256, 0, stream>>>(Ui_w, Uf_w, Uo_w, Uc_w, Wd_w, wfg);
    prep_T<<<128, 256, 0, stream>>>(tsp, Tm1);
    prep_zero<<<8, 256, 0, stream>>>(tags);
    proj_gemm<<<8192, 256, 0, stream>>>(inputs, W4, bias4, Xbuf);

    const size_t lds_bytes = 2560 * 16 + 1024 * 16 + 16 * 89 * 4
                           + 512 * 2 + 2 * 2048 * 4;   // 80,448 B
    recur<<<128, 320, lds_bytes, stream>>>(wfg, Xbuf, Wd_b, bd, Tm1,
                                           hxf, cxf, tags, (float*)d_out);
}

// Round 20
// 1286.092 us; speedup vs baseline: 1.6578x; 1.1545x over previous
//
#include <hip/hip_runtime.h>
#include <cstdint>
#include <cstddef>

// ---------------------------------------------------------------------------
// TLSTM: B=64, S=512, I=256, H=256
// R20 = R12 restored verbatim (session best: recur 1205us, total 1272us).
// Exploration summary: R13 LL-fused (1380), R14 fine-grain publish (1396),
// R17 reg-gather (1309), R18 2-cohort stagger (2070), R19 poll-overlap
// (1396) all regressed; sc0-only XCD-local variants (R11/R15) failed
// correctness. The per-step cost is compute (~700cy) + ~3 serialized
// device-scope Infinity-Cache round trips for the cross-CU h/c dependency —
// a latency floor (VALUBusy 2.8%, MfmaUtil 0.6%, HBM 2%), not a BW/compute
// roofline. Weights (640KB f16) cannot fit one CU, so the cross-CU exchange
// is structural at this problem size.
// ---------------------------------------------------------------------------

#define B_   64
#define S_   512
#define H_   256
#define BSH_ ((size_t)B_ * S_ * H_)  // 8388608

typedef _Float16 f16;
typedef _Float16 f16x8 __attribute__((ext_vector_type(8)));
typedef short    s16x8 __attribute__((ext_vector_type(8)));
typedef float    f32x4 __attribute__((ext_vector_type(4)));
typedef unsigned int u32x4 __attribute__((ext_vector_type(4)));

static __device__ __forceinline__ unsigned short f32_to_bf16(float f) {
    union { float f; uint32_t u; } v; v.f = f;
    uint32_t u = v.u;
    u += 0x7fffu + ((u >> 16) & 1u);   // RTNE
    return (unsigned short)(u >> 16);
}

static __device__ __forceinline__ float sigm(float z) {
    return 1.0f / (1.0f + __expf(-z));
}
static __device__ __forceinline__ float tanh_fast(float z) {
    float e = __expf(-2.0f * fabsf(z));
    float t = (1.0f - e) / (1.0f + e);
    return z >= 0.0f ? t : -t;
}

// ---------------------------------------------------------------------------
// prep: W4 (bf16, [1024][256]) + fused bias4 (Wg_b + b_g + Ug_b)
// ---------------------------------------------------------------------------
__global__ void prep_w4(const float* __restrict__ Wi, const float* __restrict__ Wf,
                        const float* __restrict__ Wo, const float* __restrict__ Wc,
                        const float* __restrict__ Wib, const float* __restrict__ Wfb,
                        const float* __restrict__ Wob, const float* __restrict__ Wcb,
                        const float* __restrict__ Uib, const float* __restrict__ Ufb,
                        const float* __restrict__ Uob, const float* __restrict__ Ucb,
                        const float* __restrict__ bi,  const float* __restrict__ bf_,
                        const float* __restrict__ bo,  const float* __restrict__ bc,
                        unsigned short* __restrict__ W4, float* __restrict__ bias4) {
    const int n = blockIdx.x;        // 0..1023
    const int k = threadIdx.x;       // 0..255
    const int g = n >> 8, o = n & 255;
    const float* W = (g == 0) ? Wi : (g == 1) ? Wf : (g == 2) ? Wo : Wc;
    W4[n * 256 + k] = f32_to_bf16(W[o * 256 + k]);
    if (k == 0) {
        const float* wb = (g == 0) ? Wib : (g == 1) ? Wfb : (g == 2) ? Wob : Wcb;
        const float* ub = (g == 0) ? Uib : (g == 1) ? Ufb : (g == 2) ? Uob : Ucb;
        const float* sb = (g == 0) ? bi  : (g == 1) ? bf_ : (g == 2) ? bo  : bc;
        bias4[n] = wb[o] + ub[o] + sb[o];
    }
}

// ---------------------------------------------------------------------------
// prep: weight B-fragments, fragment-linear:
// wfg[ ((q*5+g)*8+ks)*64 + l ] (uint4) = f16x8 of
//   U_g[ 16q + (l&15) ][ 32ks + (l>>4)*8 .. +8 ]
// ---------------------------------------------------------------------------
__global__ void prep_wfrag(const float* __restrict__ Ui, const float* __restrict__ Uf,
                           const float* __restrict__ Uo, const float* __restrict__ Uc,
                           const float* __restrict__ Wd, uint4* __restrict__ wfg) {
    const int id = blockIdx.x * 256 + threadIdx.x;   // 0..40959
    const int l  = id & 63;
    const int ks = (id >> 6) & 7;
    const int qg = id >> 9;          // 0..79
    const int q  = qg / 5;
    const int g  = qg - q * 5;
    const float* U = (g == 0) ? Ui : (g == 1) ? Uf : (g == 2) ? Uo : (g == 3) ? Uc : Wd;
    const int row = 16 * q + (l & 15);
    const int k0  = 32 * ks + (l >> 4) * 8;
    const float* src = U + (size_t)row * 256 + k0;
    union { f16 h[8]; uint4 v; } pk;
    #pragma unroll
    for (int i = 0; i < 8; ++i) pk.h[i] = (f16)src[i];
    wfg[id] = pk.v;
}

// prep: Tm1[m] = 1/log(ts+2.7183) - 1
__global__ void prep_T(const float* __restrict__ tsp, float* __restrict__ Tm1) {
    const int i = blockIdx.x * 256 + threadIdx.x;   // 0..32767
    Tm1[i] = 1.0f / logf(tsp[i] + 2.7183f) - 1.0f;
}

// zero the sync tags (runs every launch; graph replays it)
__global__ void prep_zero(unsigned int* __restrict__ tags) {
    tags[blockIdx.x * 256 + threadIdx.x] = 0u;
}

// ---------------------------------------------------------------------------
// Projection GEMM: Xbuf[m][j][g] f16 (gate-interleaved; recur reads uint2).
// ---------------------------------------------------------------------------
__global__ __launch_bounds__(256) void proj_gemm(const float* __restrict__ X,
        const unsigned short* __restrict__ W4, const float* __restrict__ bias4,
        f16* __restrict__ Xbuf) {
    __shared__ __align__(16) unsigned short a_s[64 * 40];
    __shared__ __align__(16) unsigned short b_s[64 * 40];
    const int bid = blockIdx.x;
    const int m0 = (bid >> 4) * 64;
    const int n0 = (bid & 15) * 64;
    const int tid  = threadIdx.x;
    const int lane = tid & 63;
    const int w    = tid >> 6;
    const int srow = tid >> 2;
    const int scol = (tid & 3) * 8;
    const int r  = lane & 15;
    const int kg = lane >> 4;

    f32x4 acc[4] = {{0,0,0,0},{0,0,0,0},{0,0,0,0},{0,0,0,0}};

    for (int kt = 0; kt < 8; ++kt) {
        const int k0 = kt * 32;
        float4 av0 = *reinterpret_cast<const float4*>(X + (size_t)(m0 + srow) * 256 + k0 + scol);
        float4 av1 = *reinterpret_cast<const float4*>(X + (size_t)(m0 + srow) * 256 + k0 + scol + 4);
        union { unsigned short us[8]; uint4 v; } pk;
        pk.us[0] = f32_to_bf16(av0.x); pk.us[1] = f32_to_bf16(av0.y);
        pk.us[2] = f32_to_bf16(av0.z); pk.us[3] = f32_to_bf16(av0.w);
        pk.us[4] = f32_to_bf16(av1.x); pk.us[5] = f32_to_bf16(av1.y);
        pk.us[6] = f32_to_bf16(av1.z); pk.us[7] = f32_to_bf16(av1.w);
        *reinterpret_cast<uint4*>(a_s + srow * 40 + scol) = pk.v;
        uint4 bv = *reinterpret_cast<const uint4*>(W4 + (size_t)(n0 + srow) * 256 + k0 + scol);
        *reinterpret_cast<uint4*>(b_s + srow * 40 + scol) = bv;
        __syncthreads();

        s16x8 af = *reinterpret_cast<const s16x8*>(a_s + (w * 16 + r) * 40 + kg * 8);
        #pragma unroll
        for (int nt = 0; nt < 4; ++nt) {
            s16x8 bfr = *reinterpret_cast<const s16x8*>(b_s + (nt * 16 + r) * 40 + kg * 8);
            acc[nt] = __builtin_amdgcn_mfma_f32_16x16x32_bf16(af, bfr, acc[nt], 0, 0, 0);
        }
        __syncthreads();
    }
    #pragma unroll
    for (int nt = 0; nt < 4; ++nt) {
        const int n = n0 + nt * 16 + r;
        const int gidx = n >> 8, jj = n & 255;
        const float bn = bias4[n];
        #pragma unroll
        for (int reg = 0; reg < 4; ++reg) {
            const int m = m0 + w * 16 + kg * 4 + reg;
            Xbuf[((size_t)m * 256 + jj) * 4 + gidx] = (f16)(acc[nt][reg] + bn);
        }
    }
}

// ---------------------------------------------------------------------------
// Recurrence. Grid 128; real blocks: G = bid&7 (<4), q = bid>>3 (0..15).
// The %8 grouping is PERF-ONLY (IC path locality); correctness rests on
// device-scope sc0 sc1 accesses through the Infinity Cache.
// ---------------------------------------------------------------------------
__global__ __launch_bounds__(320) void recur(
        const uint4* __restrict__ wfg, const f16* __restrict__ Xbuf,
        const float* __restrict__ Wdb, const float* __restrict__ bdv,
        const float* __restrict__ Tm1,
        uint4* __restrict__ hxf, uint4* __restrict__ cxf,
        unsigned int* __restrict__ tags, float* __restrict__ out) {
    extern __shared__ __align__(16) char smemraw[];
    uint4* wfr  = (uint4*)smemraw;            // 2560 units (40KB)
    uint4* hfr  = wfr + 2560;                 // 512 units  (8KB)
    uint4* cfr  = hfr + 512;                  // 512 units  (8KB)
    float* pre  = (float*)(cfr + 512);        // [16][89] f32 (5696B)
    f16*   stgh = (f16*)(pre + 16 * 89);      // 256 f16 (512B)
    f16*   stgc = stgh + 256;                 // 256 f16
    float* obh  = (float*)(stgc + 256);       // [8][256] f32 (8KB)
    float* obc  = obh + 2048;                 // [8][256] f32

    const int tid = threadIdx.x;
    const int bid = blockIdx.x;
    const int G = bid & 7;           // batch group (perf-only XCD affinity)
    const int q = bid >> 3;          // row shard 0..15
    if (G >= 4) return;              // dummy block
    const int g = tid >> 6;          // wave = matrix 0..4
    const int l = tid & 63;

    // ---- stage weight frags (global fragment-linear -> LDS linear) ----
    {
        const uint4* src = wfg + (size_t)q * 2560;
        #pragma unroll
        for (int i = 0; i < 8; ++i) wfr[tid + i * 320] = src[tid + i * 320];
    }
    // ---- zero h/c frags ----
    if (tid < 256) {
        uint4 z = {0, 0, 0, 0};
        hfr[tid] = z; hfr[tid + 256] = z;
        cfr[tid] = z; cfr[tid + 256] = z;
    }
    // gate-thread state
    const int gb = tid >> 4;         // batch 0..15  (tid<256)
    const int jl = tid & 15;         // local j
    const int j  = 16 * q + jl;      // hidden index
    float cj = 0.0f, bD = 0.0f;
    if (tid < 256) bD = Wdb[j] + bdv[j];
    __syncthreads();

    const uint4* afr = (g == 4) ? cfr : hfr;
    uint4* hxb = hxf + (size_t)G * 1024;      // [par][512]
    uint4* cxb = cxf + (size_t)G * 1024;
    unsigned int* tg = tags + (size_t)G * 512; // [par][16 slots x 16dw]

    for (int s = 0; s < 512; ++s) {
        const int par = s & 1;

        // prefetch gate inputs (consumed after barrier 1)
        uint2 xv = {0, 0};
        float tm1 = 0.f;
        size_t m = 0;
        if (tid < 256) {
            m = (size_t)(16 * G + gb) * 512 + s;
            xv  = *reinterpret_cast<const uint2*>(Xbuf + (m * 256 + j) * 4);
            tm1 = Tm1[m];
        }

        // ---- MFMA matvec: pre[batch][g*16 + jl] ----
        f32x4 acc = {0.f, 0.f, 0.f, 0.f};
        #pragma unroll
        for (int ks = 0; ks < 8; ++ks) {
            f16x8 a  = __builtin_bit_cast(f16x8, afr[ks * 64 + l]);
            f16x8 bb = __builtin_bit_cast(f16x8, wfr[(g * 8 + ks) * 64 + l]);
            acc = __builtin_amdgcn_mfma_f32_16x16x32_f16(a, bb, acc, 0, 0, 0);
        }
        {
            const int mb = (l >> 4) * 4;          // batch base (D rows)
            const int nn = g * 16 + (l & 15);     // local row (D col)
            #pragma unroll
            for (int reg = 0; reg < 4; ++reg)
                pre[(mb + reg) * 89 + nn] = acc[reg];
        }
        __syncthreads();                          // B1: preacts ready

        // ---- gates (threads 0..255, 1 (batch,j) pair each) ----
        if (tid < 256) {
            const float* pb = pre + gb * 89;
            const f16* xp = reinterpret_cast<const f16*>(&xv);
            float CST  = tanh_fast(pb[64 + jl] + bD);
            float cdec = cj + tm1 * CST;
            float ig = sigm((float)xp[0] + pb[jl]);
            float fg = sigm((float)xp[1] + pb[16 + jl]);
            float og = sigm((float)xp[2] + pb[32 + jl]);
            float Cn = tanh_fast((float)xp[3] + pb[48 + jl]);
            cj = fg * cdec + ig * Cn;
            float hn = og * tanh_fast(cj);
            stgh[tid] = (f16)hn;
            stgc[tid] = (f16)cj;
            obh[(s & 7) * 256 + tid] = hn;
            obc[(s & 7) * 256 + tid] = cj;
        }
        __syncthreads();                          // B2: staging/obuf ready

        if (s != 511) {
            // ---- publish own h/c chunk, device-coherent via IC (sc0 sc1) ----
            if (tid < 64) {
                const int b   = tid & 15;
                const int kgo = (tid >> 4) & 1;
                const bool isC = tid >= 32;
                u32x4 v = __builtin_bit_cast(u32x4, *reinterpret_cast<const uint4*>(
                    (isC ? stgc : stgh) + b * 16 + kgo * 8));
                const int u = (q >> 1) * 64 + ((q & 1) * 2 + kgo) * 16 + b;
                uint4* pp = (isC ? cxb : hxb) + par * 512 + u;
                asm volatile("global_store_dwordx4 %0, %1, off sc0 sc1"
                             :: "v"(pp), "v"(v) : "memory");
                // publish stores acked at the coherence point -> release tag
                asm volatile("s_waitcnt vmcnt(0)" ::: "memory");
                if (tid == 0) {
                    unsigned int* tp = tg + par * 256 + q * 16;
                    unsigned tagv = (unsigned)(s + 1);
                    asm volatile("global_store_dword %0, %1, off sc0 sc1"
                                 :: "v"(tp), "v"(tagv) : "memory");
                }
            }
        }
        // ---- output flush every 8 steps (overlaps partner wait) ----
        if ((s & 7) == 7 && tid < 256) {
            #pragma unroll
            for (int sf = 0; sf < 8; ++sf) {
                const size_t mm = (size_t)(16 * G + gb) * 512 + (s - 7 + sf);
                const size_t oi = mm * 256 + j;
                float hv = obh[sf * 256 + tid];
                float cv = obc[sf * 256 + tid];
                out[oi] = hv; out[BSH_ + oi] = hv; out[2 * BSH_ + oi] = cv;
            }
        }
        if (s != 511) {
            // ---- poll 16 partners, device-coherent loads (sc0 sc1) ----
            if (tid < 16) {
                const unsigned int* tp = tg + par * 256 + tid * 16;
                unsigned v;
                int spins = 0;
                for (;;) {
                    asm volatile("global_load_dword %0, %1, off sc0 sc1\n\t"
                                 "s_waitcnt vmcnt(0)"
                                 : "=v"(v) : "v"(tp) : "memory");
                    if (v >= (unsigned)(s + 1)) break;
                    if (++spins > (1 << 22)) break;   // timeout insurance only
                    __builtin_amdgcn_s_sleep(1);
                }
            }
            __syncthreads();                      // B3: all chunks published
            // ---- gather full h/c frags from IC (sc0 sc1, pipelined) ----
            if (tid < 256) {
                const uint4* p0 = hxb + par * 512 + tid;
                const uint4* p1 = hxb + par * 512 + tid + 256;
                const uint4* p2 = cxb + par * 512 + tid;
                const uint4* p3 = cxb + par * 512 + tid + 256;
                u32x4 va, vb, vc, vd;
                asm volatile(
                    "global_load_dwordx4 %0, %4, off sc0 sc1\n\t"
                    "global_load_dwordx4 %1, %5, off sc0 sc1\n\t"
                    "global_load_dwordx4 %2, %6, off sc0 sc1\n\t"
                    "global_load_dwordx4 %3, %7, off sc0 sc1\n\t"
                    "s_waitcnt vmcnt(0)"
                    : "=&v"(va), "=&v"(vb), "=&v"(vc), "=&v"(vd)
                    : "v"(p0), "v"(p1), "v"(p2), "v"(p3)
                    : "memory");
                hfr[tid]       = __builtin_bit_cast(uint4, va);
                hfr[tid + 256] = __builtin_bit_cast(uint4, vb);
                cfr[tid]       = __builtin_bit_cast(uint4, vc);
                cfr[tid + 256] = __builtin_bit_cast(uint4, vd);
            }
        }
        __syncthreads();                          // B4: frags ready / flush done
    }
}

// ---------------------------------------------------------------------------
extern "C" void kernel_launch(void* const* d_in, const int* in_sizes, int n_in,
                              void* d_out, int out_size, void* d_ws, size_t ws_size,
                              hipStream_t stream) {
    const float* inputs = (const float*)d_in[0];
    const float* tsp    = (const float*)d_in[1];
    const float* Wi_w = (const float*)d_in[2],  * Wi_b = (const float*)d_in[3];
    const float* Ui_w = (const float*)d_in[4],  * Ui_b = (const float*)d_in[5];
    const float* Wf_w = (const float*)d_in[6],  * Wf_b = (const float*)d_in[7];
    const float* Uf_w = (const float*)d_in[8],  * Uf_b = (const float*)d_in[9];
    const float* Wo_w = (const float*)d_in[10], * Wo_b = (const float*)d_in[11];
    const float* Uo_w = (const float*)d_in[12], * Uo_b = (const float*)d_in[13];
    const float* Wc_w = (const float*)d_in[14], * Wc_b = (const float*)d_in[15];
    const float* Uc_w = (const float*)d_in[16], * Uc_b = (const float*)d_in[17];
    const float* Wd_w = (const float*)d_in[18], * Wd_b = (const float*)d_in[19];
    const float* bi = (const float*)d_in[20], * bf_ = (const float*)d_in[21];
    const float* bo = (const float*)d_in[22], * bc  = (const float*)d_in[23];
    const float* bd = (const float*)d_in[24];

    // workspace layout (16B-aligned):
    //   Xbuf  f16   [32768][256][4]  67,108,864 B @ 0
    //   W4    bf16  [1024][256]         524,288 B @ 67,108,864
    //   bias4 f32   [1024]                4,096 B @ 67,633,152
    //   wfg   uint4 [40960]             655,360 B @ 67,637,248
    //   hxf   uint4 [4][2][512]          65,536 B @ 68,292,608
    //   cxf   uint4 [4][2][512]          65,536 B @ 68,358,144
    //   Tm1   f32   [32768]             131,072 B @ 68,423,680
    //   tags  u32   [4][2][16][16]        8,192 B @ 68,554,752
    char* ws = (char*)d_ws;
    f16*            Xbuf  = (f16*)ws;
    unsigned short* W4    = (unsigned short*)(ws + 67108864);
    float*          bias4 = (float*)(ws + 67633152);
    uint4*          wfg   = (uint4*)(ws + 67637248);
    uint4*          hxf   = (uint4*)(ws + 68292608);
    uint4*          cxf   = (uint4*)(ws + 68358144);
    float*          Tm1   = (float*)(ws + 68423680);
    unsigned int*   tags  = (unsigned int*)(ws + 68554752);

    prep_w4<<<1024, 256, 0, stream>>>(Wi_w, Wf_w, Wo_w, Wc_w,
                                      Wi_b, Wf_b, Wo_b, Wc_b,
                                      Ui_b, Uf_b, Uo_b, Uc_b,
                                      bi, bf_, bo, bc, W4, bias4);
    prep_wfrag<<<160, 256, 0, stream>>>(Ui_w, Uf_w, Uo_w, Uc_w, Wd_w, wfg);
    prep_T<<<128, 256, 0, stream>>>(tsp, Tm1);
    prep_zero<<<8, 256, 0, stream>>>(tags);
    proj_gemm<<<8192, 256, 0, stream>>>(inputs, W4, bias4, Xbuf);

    const size_t lds_bytes = 2560 * 16 + 1024 * 16 + 16 * 89 * 4
                           + 512 * 2 + 2 * 2048 * 4;   // 80,448 B
    recur<<<128, 320, lds_bytes, stream>>>(wfg, Xbuf, Wd_b, bd, Tm1,
                                           hxf, cxf, tags, (float*)d_out);
}